// Round 16
// baseline (207.433 us; speedup 1.0000x reference)
//
#include <hip/hip_runtime.h>
#include <hip/hip_bf16.h>

#define B_N 4096
#define T_N 64
#define D_N 256
#define H_N 128
#define K_N 12

typedef __attribute__((ext_vector_type(8))) short short8;
typedef __attribute__((ext_vector_type(4))) float f32x4;

static __device__ __forceinline__ unsigned bf16_rne(float x) {
  unsigned u = __float_as_uint(x);
  return (u + 0x7fffu + ((u >> 16) & 1u)) >> 16;
}
static __device__ __forceinline__ unsigned pk2(float a, float b) {
  return bf16_rne(a) | (bf16_rne(b) << 16);
}
static __device__ __forceinline__ float lo16(unsigned u) { return __uint_as_float(u << 16); }
static __device__ __forceinline__ float hi16(unsigned u) { return __uint_as_float(u & 0xffff0000u); }

// ---------------------------------------------------------------------------
// prep_all: ONE kernel replacing prep_wa + 3x prep_w + stats memset.
// ---------------------------------------------------------------------------
__device__ __forceinline__ void pack_w(const float* W, unsigned* out, int S, int id) {
  const int lane = id & 63;
  const int s  = (id >> 6) % S;
  const int nt = ((id >> 6) / S) & 7;
  const int kk = id / (64 * S * 8);
  const int n  = nt * 16 + (lane & 15);
  const int d0 = 32 * s + 8 * (lane >> 4);
  const int D  = 32 * S;
  unsigned o[4];
#pragma unroll
  for (int j = 0; j < 4; ++j) {
    const float a = W[(size_t)kk * D * H_N + (d0 + 2 * j) * H_N + n];
    const float b = W[(size_t)kk * D * H_N + (d0 + 2 * j + 1) * H_N + n];
    o[j] = pk2(a, b);
  }
  *(uint4*)(out + (size_t)id * 4) = make_uint4(o[0], o[1], o[2], o[3]);
}

__global__ void prep_all(const float* __restrict__ w_atom,
                         const float* __restrict__ W1, const float* __restrict__ W2,
                         const float* __restrict__ W3,
                         unsigned* __restrict__ wa_frag, unsigned* __restrict__ w1p,
                         unsigned* __restrict__ w2p, unsigned* __restrict__ w3p,
                         float* __restrict__ st)
{
  const int bid = blockIdx.x, tid = threadIdx.x;
  if (bid < 2) {
    const int id = bid * 256 + tid;          // [0,512)
    const int s = id >> 6, l = id & 63;
    const int k = l & 15, h = l >> 4, d0 = s * 32 + h * 8;
    unsigned o[4];
#pragma unroll
    for (int j = 0; j < 4; ++j) {
      const float a = (k < K_N) ? w_atom[k * D_N + d0 + 2 * j]     : 0.f;
      const float b = (k < K_N) ? w_atom[k * D_N + d0 + 2 * j + 1] : 0.f;
      o[j] = pk2(a, b);
    }
    *(uint4*)(wa_frag + (size_t)id * 4) = make_uint4(o[0], o[1], o[2], o[3]);
  } else if (bid < 194) {
    pack_w(W1, w1p, 8, (bid - 2) * 256 + tid);
  } else if (bid < 290) {
    pack_w(W2, w2p, 4, (bid - 194) * 256 + tid);
  } else if (bid < 386) {
    pack_w(W3, w3p, 4, (bid - 290) * 256 + tid);
  } else {
    const int id = (bid - 386) * 256 + tid;
    if (id < 9216) st[id] = 0.f;
  }
}

// ---------------------------------------------------------------------------
// K1 half-tile / high-occupancy: 128 threads (2 waves), one b per block,
// TWO sequential half-tiles (t = 0..31, 32..63) through a 16 KB LDS tile.
// LDS = 16 KB tile + 3.3 KB wv32 = 19.6 KB -> 8 blocks/CU (16 waves, was 4
// blocks/16 waves at 256thr but with 2x the stage bursts and 2x independent
// blocks for load-phase staggering).  Per half (R13-verified structure):
//   stage own 16 rows (no barrier; p1 reads only own rows) -> p1 (8 MFMA,
//   C[t,k]) -> sigmoid -> wv32 -> barrier -> p2 scalar accumulate.
// Swizzle algebra identical to R13: u32 off = rl*128 + (((d>>3)^(rl&15))<<2)
// + ((d>>2)&1)*2, rl = t & 31 (rl&15 == k for both waves).
// ---------------------------------------------------------------------------
__global__ __launch_bounds__(128, 4) void k1_mol(
    const int* __restrict__ dx, const float* __restrict__ feats,
    const unsigned* __restrict__ wa_frag, const float* __restrict__ b_atom,
    float* __restrict__ out_atom, unsigned short* __restrict__ mol16)
{
  __shared__ unsigned tile[32 * 128];   // 16 KB bf16 half-tile, swizzled
  __shared__ float wv32[K_N * 68];      // 3264 B, stride-68 rows

  const int tid  = threadIdx.x;
  const int lane = tid & 63;
  const int w    = tid >> 6;            // 0 or 1
  const int b    = blockIdx.x;
  const int k    = lane & 15;
  const int h    = lane >> 4;

  short8 bfr[8];
  {
    const short8* wf8 = (const short8*)wa_frag;
#pragma unroll
    for (int s = 0; s < 8; ++s) bfr[s] = wf8[s * 64 + lane];
  }
  const float ba = (k < K_N) ? b_atom[k] : 0.f;

  const float* fg = feats + ((size_t)b * 65 + 1) * 256;

  // p2 accumulators: wave owns k = 6w..6w+5, lane owns d = 4*lane..+3
  float4 m[6];
#pragma unroll
  for (int kk = 0; kk < 6; ++kk) m[kk] = make_float4(0.f, 0.f, 0.f, 0.f);
  const int kb = 6 * w;

#pragma unroll
  for (int H = 0; H < 2; ++H) {
    if (H) __syncthreads();   // previous half's p2 reads done before restage

    // ---- stage own 16 rows (rl = 16w..16w+15) -----------------------------
#pragma unroll
    for (int c = 0; c < 4; ++c) {
      float4 v[4];
#pragma unroll
      for (int i = 0; i < 4; ++i)
        v[i] = *(const float4*)(fg + (size_t)(32 * H + 16 * w + 4 * c + i) * 256 + 4 * lane);
#pragma unroll
      for (int i = 0; i < 4; ++i) {
        const int tl = 4 * c + i;              // 0..15
        const int rl = 16 * w + tl;            // LDS row 0..31
        const unsigned off = rl * 128 + (((lane >> 1) ^ (rl & 15)) << 2) + (lane & 1) * 2;
        *(uint2*)&tile[off] = make_uint2(pk2(v[i].x, v[i].y), pk2(v[i].z, v[i].w));
      }
    }
    // No barrier: p1 reads only this wave's rows (same-wave lgkmcnt order).

    // ---- phase 1: C[t,k] via 8 mfma steps ---------------------------------
    f32x4 cacc = {0.f, 0.f, 0.f, 0.f};
#pragma unroll
    for (int s = 0; s < 8; ++s) {
      const unsigned off = (16 * w + k) * 128 + (((4 * s + h) ^ k) << 2);
      const short8 afrag = *(const short8*)&tile[off];
      cacc = __builtin_amdgcn_mfma_f32_16x16x32_bf16(afrag, bfr[s], cacc, 0, 0, 0);
    }

    // ---- phase 1.5: wv = valid * sigmoid(C + ba) -> wv32 ------------------
    const int4 dvv = *(const int4*)(dx + b * T_N + 32 * H + 16 * w + 4 * h);
#pragma unroll
    for (int r = 0; r < 4; ++r) {
      const float valid = (((const int*)&dvv)[r] != 0) ? 1.f : 0.f;
      const float wv = valid / (1.f + __expf(-(cacc[r] + ba)));
      if (k < K_N) wv32[k * 68 + 32 * H + 16 * w + 4 * h + r] = wv;
    }
    __syncthreads();   // wv32 + full half-tile visible before p2

    // ---- phase 2: accumulate over this half's 32 t ------------------------
#pragma unroll
    for (int tc = 0; tc < 8; ++tc) {
      float4 wvv[6];
#pragma unroll
      for (int kk = 0; kk < 6; ++kk)
        wvv[kk] = *(const float4*)&wv32[(kb + kk) * 68 + 32 * H + (tc << 2)];
#pragma unroll
      for (int j = 0; j < 4; ++j) {
        const int rl = (tc << 2) + j;
        const unsigned off = rl * 128 + (((lane >> 1) ^ (rl & 15)) << 2) + (lane & 1) * 2;
        const uint2 pw = *(const uint2*)&tile[off];
        const float f0 = lo16(pw.x), f1 = hi16(pw.x);
        const float f2 = lo16(pw.y), f3 = hi16(pw.y);
#pragma unroll
        for (int kk = 0; kk < 6; ++kk) {
          const float wj = ((const float*)&wvv[kk])[j];
          m[kk].x = fmaf(wj, f0, m[kk].x); m[kk].y = fmaf(wj, f1, m[kk].y);
          m[kk].z = fmaf(wj, f2, m[kk].z); m[kk].w = fmaf(wj, f3, m[kk].w);
        }
      }
    }
  }

  // ---- store mol (bf16): wave w owns k = 6w..6w+5, lane d = 4*lane --------
#pragma unroll
  for (int kk = 0; kk < 6; ++kk) {
    unsigned short* mp = mol16 + ((size_t)(kb + kk) * B_N + b) * 256 + 4 * lane;
    *(uint2*)mp = make_uint2(pk2(m[kk].x, m[kk].y), pk2(m[kk].z, m[kk].w));
  }

  // ---- coalesced atom_out write from wv32 ---------------------------------
#pragma unroll
  for (int i = tid; i < 192; i += 128) {
    const int kk = i >> 4, t0 = (i & 15) * 4;
    const float4 v = *(const float4*)&wv32[kk * 68 + t0];
    *(float4*)&out_atom[((size_t)kk * B_N + b) * T_N + t0] = v;
  }
}

// ---------------------------------------------------------------------------
// MFMA GEMM layer (unchanged; folded bn_coef in AFFINE prologue).
// ---------------------------------------------------------------------------
template <int S, bool AFFINE>
__global__ __launch_bounds__(256) void gemm_mfma(
    const unsigned* __restrict__ Abf, const unsigned* __restrict__ wpack,
    const float* __restrict__ bias,
    const float* __restrict__ ssum_p, const float* __restrict__ ssq_p,
    const float* __restrict__ g_p, const float* __restrict__ be_p,
    unsigned short* __restrict__ Hout,
    float* __restrict__ ssum, float* __restrict__ ssq)
{
  __shared__ unsigned tile[64 * S * 16];
  __shared__ float redS[4][8][16];
  __shared__ float redQ[4][8][16];
  __shared__ float alds[H_N], blds[H_N];

  const int k   = blockIdx.y;
  const int b0  = blockIdx.x << 6;
  const int tid = threadIdx.x;
  const int lane = tid & 63;
  const int wv  = tid >> 6;
  const int ln15 = lane & 15;
  const int hq   = lane >> 4;

  if (AFFINE) {
    if (tid < H_N) {
      const float inv_n = 1.f / (float)B_N;
      const float m = ssum_p[k * H_N + tid] * inv_n;
      float v = fmaf(ssq_p[k * H_N + tid], inv_n, -m * m);
      v = fmaxf(v, 0.f);
      const float a = g_p[k * H_N + tid] * rsqrtf(v + 1e-5f);
      alds[tid] = a;
      blds[tid] = fmaf(-m, a, be_p[k * H_N + tid]);
    }
    __syncthreads();
  }

  {
    const int row = tid >> 2, q = tid & 3;
    const uint4* Ar = (const uint4*)Abf + ((size_t)k * B_N + b0 + row) * (S * 4) + q * S;
#pragma unroll
    for (int gi = 0; gi < S; ++gi) {
      const int g = q * S + gi;
      uint4 u = Ar[gi];
      if (AFFINE) {
        const float4 al0 = *(const float4*)(alds + g * 8);
        const float4 al1 = *(const float4*)(alds + g * 8 + 4);
        const float4 bt0 = *(const float4*)(blds + g * 8);
        const float4 bt1 = *(const float4*)(blds + g * 8 + 4);
        u.x = pk2(fmaf(lo16(u.x), al0.x, bt0.x), fmaf(hi16(u.x), al0.y, bt0.y));
        u.y = pk2(fmaf(lo16(u.y), al0.z, bt0.z), fmaf(hi16(u.y), al0.w, bt0.w));
        u.z = pk2(fmaf(lo16(u.z), al1.x, bt1.x), fmaf(hi16(u.z), al1.y, bt1.y));
        u.w = pk2(fmaf(lo16(u.w), al1.z, bt1.z), fmaf(hi16(u.w), al1.w, bt1.w));
      }
      *(uint4*)&tile[row * (S * 16) + ((g ^ (row & 15)) << 2)] = u;
    }
  }
  __syncthreads();

  const short8* wp8 = (const short8*)wpack + (size_t)k * 8 * S * 64 + lane;
  f32x4 acc[8];
#pragma unroll
  for (int nt = 0; nt < 8; ++nt) acc[nt] = (f32x4){0.f, 0.f, 0.f, 0.f};

  short8 bs0[8], bs1[8];
#pragma unroll
  for (int nt = 0; nt < 8; ++nt) bs0[nt] = wp8[(nt * S) * 64];
#pragma unroll
  for (int s = 0; s < S; ++s) {
    if (s + 1 < S) {
#pragma unroll
      for (int nt = 0; nt < 8; ++nt) {
        if (s & 1) bs0[nt] = wp8[(nt * S + s + 1) * 64];
        else       bs1[nt] = wp8[(nt * S + s + 1) * 64];
      }
    }
    const int arow = (wv << 4) + ln15;
    const unsigned aoff = arow * (S * 16) + (((4 * s + hq) ^ ln15) << 2);
    const short8 af = *(const short8*)&tile[aoff];
#pragma unroll
    for (int nt = 0; nt < 8; ++nt) {
      const short8 bf = (s & 1) ? bs1[nt] : bs0[nt];
      acc[nt] = __builtin_amdgcn_mfma_f32_16x16x32_bf16(af, bf, acc[nt], 0, 0, 0);
    }
  }

#pragma unroll
  for (int nt = 0; nt < 8; ++nt) {
    const int col = nt * 16 + ln15;
    const float bv = bias[k * H_N + col];
    float cs = 0.f, cq = 0.f;
#pragma unroll
    for (int r = 0; r < 4; ++r) {
      const float o = fmaxf(acc[nt][r] + bv, 0.f);
      cs += o; cq = fmaf(o, o, cq);
      const int row = b0 + (wv << 4) + (hq << 2) + r;
      Hout[((size_t)k * B_N + row) * H_N + col] = (unsigned short)bf16_rne(o);
    }
    cs += __shfl_xor(cs, 16); cs += __shfl_xor(cs, 32);
    cq += __shfl_xor(cq, 16); cq += __shfl_xor(cq, 32);
    if (lane < 16) { redS[wv][nt][ln15] = cs; redQ[wv][nt][ln15] = cq; }
  }
  __syncthreads();
  if (tid < 128) {
    const int nt = tid >> 4, c = tid & 15;
    float s = 0.f, q = 0.f;
#pragma unroll
    for (int i = 0; i < 4; ++i) { s += redS[i][nt][c]; q += redQ[i][nt][c]; }
    atomicAdd(&ssum[k * H_N + nt * 16 + c], s);
    atomicAdd(&ssq[k * H_N + nt * 16 + c], q);
  }
}

// ---------------------------------------------------------------------------
// k_pred with folded bn3 (unchanged).
// ---------------------------------------------------------------------------
__global__ __launch_bounds__(256) void k_pred(
    const unsigned* __restrict__ h3,
    const float* __restrict__ s3, const float* __restrict__ q3,
    const float* __restrict__ g3, const float* __restrict__ be3,
    const float* __restrict__ Wout, const float* __restrict__ bout,
    float* __restrict__ out)
{
  const int lane = threadIdx.x & 63;
  const int wv   = threadIdx.x >> 6;
  const int pair = blockIdx.x * 4 + wv;
  const int b = pair / K_N, k = pair - b * K_N;
  const int i0 = k * H_N + (lane << 1);

  const float inv_n = 1.f / (float)B_N;
  const float2 sv = *(const float2*)(s3 + i0);
  const float2 qv = *(const float2*)(q3 + i0);
  const float2 gv = *(const float2*)(g3 + i0);
  const float2 bev = *(const float2*)(be3 + i0);
  const float mx = sv.x * inv_n, my = sv.y * inv_n;
  const float vx = fmaxf(fmaf(qv.x, inv_n, -mx * mx), 0.f);
  const float vy = fmaxf(fmaf(qv.y, inv_n, -my * my), 0.f);
  const float ax = gv.x * rsqrtf(vx + 1e-5f);
  const float ay = gv.y * rsqrtf(vy + 1e-5f);
  const float bx = fmaf(-mx, ax, bev.x);
  const float by = fmaf(-my, ay, bev.y);

  const unsigned xp = h3[((size_t)k * B_N + b) * 64 + lane];
  const float2 wo = *(const float2*)(Wout + i0);
  float s = fmaf(lo16(xp), ax, bx) * wo.x + fmaf(hi16(xp), ay, by) * wo.y;
#pragma unroll
  for (int off = 32; off; off >>= 1) s += __shfl_down(s, off);
  if (lane == 0) out[pair] = s + bout[k];
}

extern "C" void kernel_launch(void* const* d_in, const int* in_sizes, int n_in,
                              void* d_out, int out_size, void* d_ws, size_t ws_size,
                              hipStream_t stream)
{
  (void)in_sizes; (void)n_in; (void)out_size; (void)ws_size;
  const int*   dx     = (const int*)d_in[0];
  const float* feats  = (const float*)d_in[1];
  const float* w_atom = (const float*)d_in[2];
  const float* b_atom = (const float*)d_in[3];
  const float* W1 = (const float*)d_in[4];
  const float* b1 = (const float*)d_in[5];
  const float* g1 = (const float*)d_in[6];
  const float* be1 = (const float*)d_in[7];
  const float* W2 = (const float*)d_in[8];
  const float* b2 = (const float*)d_in[9];
  const float* g2 = (const float*)d_in[10];
  const float* be2 = (const float*)d_in[11];
  const float* W3 = (const float*)d_in[12];
  const float* b3 = (const float*)d_in[13];
  const float* g3 = (const float*)d_in[14];
  const float* be3 = (const float*)d_in[15];
  const float* Wout = (const float*)d_in[16];
  const float* bout = (const float*)d_in[17];

  float* out      = (float*)d_out;
  float* pred_out = out;                       // (B, K)
  float* atom_out = out + (size_t)B_N * K_N;   // (K, B, T)

  // ---- workspace layout (bytes) ----
  char* wsb = (char*)d_ws;
  unsigned short* mol16 = (unsigned short*)wsb;                // bf16 K*B*D
  unsigned short* h1   = (unsigned short*)(wsb + 25165824);
  unsigned short* h2   = (unsigned short*)(wsb + 37748736);
  unsigned short* h3   = (unsigned short*)(wsb + 50331648);
  float* st = (float*)(wsb + 62914560);                        // 9216 floats
  float* s1 = st,        *q1 = st + 1536;
  float* s2 = st + 3072, *q2 = st + 4608;
  float* s3 = st + 6144, *q3 = st + 7680;
  unsigned* wa_frag = (unsigned*)(st + 9216);
  unsigned* w1p = wa_frag + 2048;
  unsigned* w2p = w1p + 196608;
  unsigned* w3p = w2p + 98304;

  prep_all<<<422, 256, 0, stream>>>(w_atom, W1, W2, W3, wa_frag, w1p, w2p, w3p, st);

  k1_mol<<<B_N, 128, 0, stream>>>(dx, feats, wa_frag, b_atom, atom_out, mol16);

  gemm_mfma<8, false><<<dim3(64, 12), 256, 0, stream>>>(
      (const unsigned*)mol16, w1p, b1, nullptr, nullptr, nullptr, nullptr, h1, s1, q1);
  gemm_mfma<4, true><<<dim3(64, 12), 256, 0, stream>>>(
      (const unsigned*)h1, w2p, b2, s1, q1, g1, be1, h2, s2, q2);
  gemm_mfma<4, true><<<dim3(64, 12), 256, 0, stream>>>(
      (const unsigned*)h2, w3p, b3, s2, q2, g2, be2, h3, s3, q3);
  k_pred<<<B_N * K_N / 4, 256, 0, stream>>>(
      (const unsigned*)h3, s3, q3, g3, be3, Wout, bout, pred_out);
}

// Round 17
// 133.457 us; speedup vs baseline: 1.5543x; 1.5543x over previous
//
#include <hip/hip_runtime.h>
#include <hip/hip_bf16.h>

#define B_N 4096
#define T_N 64
#define D_N 256
#define H_N 128
#define K_N 12

typedef __attribute__((ext_vector_type(8))) short short8;
typedef __attribute__((ext_vector_type(4))) float f32x4;

static __device__ __forceinline__ unsigned bf16_rne(float x) {
  unsigned u = __float_as_uint(x);
  return (u + 0x7fffu + ((u >> 16) & 1u)) >> 16;
}
static __device__ __forceinline__ unsigned pk2(float a, float b) {
  return bf16_rne(a) | (bf16_rne(b) << 16);
}
static __device__ __forceinline__ float lo16(unsigned u) { return __uint_as_float(u << 16); }
static __device__ __forceinline__ float hi16(unsigned u) { return __uint_as_float(u & 0xffff0000u); }

// ---------------------------------------------------------------------------
// prep_all: ONE kernel replacing prep_wa + 3x prep_w + stats memset.
// ---------------------------------------------------------------------------
__device__ __forceinline__ void pack_w(const float* W, unsigned* out, int S, int id) {
  const int lane = id & 63;
  const int s  = (id >> 6) % S;
  const int nt = ((id >> 6) / S) & 7;
  const int kk = id / (64 * S * 8);
  const int n  = nt * 16 + (lane & 15);
  const int d0 = 32 * s + 8 * (lane >> 4);
  const int D  = 32 * S;
  unsigned o[4];
#pragma unroll
  for (int j = 0; j < 4; ++j) {
    const float a = W[(size_t)kk * D * H_N + (d0 + 2 * j) * H_N + n];
    const float b = W[(size_t)kk * D * H_N + (d0 + 2 * j + 1) * H_N + n];
    o[j] = pk2(a, b);
  }
  *(uint4*)(out + (size_t)id * 4) = make_uint4(o[0], o[1], o[2], o[3]);
}

__global__ void prep_all(const float* __restrict__ w_atom,
                         const float* __restrict__ W1, const float* __restrict__ W2,
                         const float* __restrict__ W3,
                         unsigned* __restrict__ wa_frag, unsigned* __restrict__ w1p,
                         unsigned* __restrict__ w2p, unsigned* __restrict__ w3p,
                         float* __restrict__ st)
{
  const int bid = blockIdx.x, tid = threadIdx.x;
  if (bid < 2) {
    const int id = bid * 256 + tid;          // [0,512)
    const int s = id >> 6, l = id & 63;
    const int k = l & 15, h = l >> 4, d0 = s * 32 + h * 8;
    unsigned o[4];
#pragma unroll
    for (int j = 0; j < 4; ++j) {
      const float a = (k < K_N) ? w_atom[k * D_N + d0 + 2 * j]     : 0.f;
      const float b = (k < K_N) ? w_atom[k * D_N + d0 + 2 * j + 1] : 0.f;
      o[j] = pk2(a, b);
    }
    *(uint4*)(wa_frag + (size_t)id * 4) = make_uint4(o[0], o[1], o[2], o[3]);
  } else if (bid < 194) {
    pack_w(W1, w1p, 8, (bid - 2) * 256 + tid);
  } else if (bid < 290) {
    pack_w(W2, w2p, 4, (bid - 194) * 256 + tid);
  } else if (bid < 386) {
    pack_w(W3, w3p, 4, (bid - 290) * 256 + tid);
  } else {
    const int id = (bid - 386) * 256 + tid;
    if (id < 9216) st[id] = 0.f;
  }
}

// ---------------------------------------------------------------------------
// K1 half-tile / high-occupancy (R16 structure, SPILL FIX): 128 threads,
// one b per block, two half-tiles through 16 KB LDS.  R16's
// __launch_bounds__(128,4) drove the allocator to a 64-VGPR target
// (8 waves/EU -- unobtainable: LDS caps at 4/EU) and spilled ~90 live
// values -> 218 MB scratch writes (vs 38 MB real).  Plain (128) lets the
// allocator take ~96-128 VGPRs; reg granularity still gives 4 waves/EU,
// so the LDS-capped 8 blocks/CU is unchanged.
// ---------------------------------------------------------------------------
__global__ __launch_bounds__(128) void k1_mol(
    const int* __restrict__ dx, const float* __restrict__ feats,
    const unsigned* __restrict__ wa_frag, const float* __restrict__ b_atom,
    float* __restrict__ out_atom, unsigned short* __restrict__ mol16)
{
  __shared__ unsigned tile[32 * 128];   // 16 KB bf16 half-tile, swizzled
  __shared__ float wv32[K_N * 68];      // 3264 B, stride-68 rows

  const int tid  = threadIdx.x;
  const int lane = tid & 63;
  const int w    = tid >> 6;            // 0 or 1
  const int b    = blockIdx.x;
  const int k    = lane & 15;
  const int h    = lane >> 4;

  short8 bfr[8];
  {
    const short8* wf8 = (const short8*)wa_frag;
#pragma unroll
    for (int s = 0; s < 8; ++s) bfr[s] = wf8[s * 64 + lane];
  }
  const float ba = (k < K_N) ? b_atom[k] : 0.f;

  const float* fg = feats + ((size_t)b * 65 + 1) * 256;

  // p2 accumulators: wave owns k = 6w..6w+5, lane owns d = 4*lane..+3
  float4 m[6];
#pragma unroll
  for (int kk = 0; kk < 6; ++kk) m[kk] = make_float4(0.f, 0.f, 0.f, 0.f);
  const int kb = 6 * w;

#pragma unroll
  for (int H = 0; H < 2; ++H) {
    if (H) __syncthreads();   // previous half's p2 reads done before restage

    // ---- stage own 16 rows (rl = 16w..16w+15) -----------------------------
#pragma unroll
    for (int c = 0; c < 4; ++c) {
      float4 v[4];
#pragma unroll
      for (int i = 0; i < 4; ++i)
        v[i] = *(const float4*)(fg + (size_t)(32 * H + 16 * w + 4 * c + i) * 256 + 4 * lane);
#pragma unroll
      for (int i = 0; i < 4; ++i) {
        const int tl = 4 * c + i;              // 0..15
        const int rl = 16 * w + tl;            // LDS row 0..31
        const unsigned off = rl * 128 + (((lane >> 1) ^ (rl & 15)) << 2) + (lane & 1) * 2;
        *(uint2*)&tile[off] = make_uint2(pk2(v[i].x, v[i].y), pk2(v[i].z, v[i].w));
      }
    }
    // No barrier: p1 reads only this wave's rows (same-wave lgkmcnt order).

    // ---- phase 1: C[t,k] via 8 mfma steps ---------------------------------
    f32x4 cacc = {0.f, 0.f, 0.f, 0.f};
#pragma unroll
    for (int s = 0; s < 8; ++s) {
      const unsigned off = (16 * w + k) * 128 + (((4 * s + h) ^ k) << 2);
      const short8 afrag = *(const short8*)&tile[off];
      cacc = __builtin_amdgcn_mfma_f32_16x16x32_bf16(afrag, bfr[s], cacc, 0, 0, 0);
    }

    // ---- phase 1.5: wv = valid * sigmoid(C + ba) -> wv32 ------------------
    const int4 dvv = *(const int4*)(dx + b * T_N + 32 * H + 16 * w + 4 * h);
#pragma unroll
    for (int r = 0; r < 4; ++r) {
      const float valid = (((const int*)&dvv)[r] != 0) ? 1.f : 0.f;
      const float wv = valid / (1.f + __expf(-(cacc[r] + ba)));
      if (k < K_N) wv32[k * 68 + 32 * H + 16 * w + 4 * h + r] = wv;
    }
    __syncthreads();   // wv32 + full half-tile visible before p2

    // ---- phase 2: accumulate over this half's 32 t ------------------------
#pragma unroll
    for (int tc = 0; tc < 8; ++tc) {
      float4 wvv[6];
#pragma unroll
      for (int kk = 0; kk < 6; ++kk)
        wvv[kk] = *(const float4*)&wv32[(kb + kk) * 68 + 32 * H + (tc << 2)];
#pragma unroll
      for (int j = 0; j < 4; ++j) {
        const int rl = (tc << 2) + j;
        const unsigned off = rl * 128 + (((lane >> 1) ^ (rl & 15)) << 2) + (lane & 1) * 2;
        const uint2 pw = *(const uint2*)&tile[off];
        const float f0 = lo16(pw.x), f1 = hi16(pw.x);
        const float f2 = lo16(pw.y), f3 = hi16(pw.y);
#pragma unroll
        for (int kk = 0; kk < 6; ++kk) {
          const float wj = ((const float*)&wvv[kk])[j];
          m[kk].x = fmaf(wj, f0, m[kk].x); m[kk].y = fmaf(wj, f1, m[kk].y);
          m[kk].z = fmaf(wj, f2, m[kk].z); m[kk].w = fmaf(wj, f3, m[kk].w);
        }
      }
    }
  }

  // ---- store mol (bf16): wave w owns k = 6w..6w+5, lane d = 4*lane --------
#pragma unroll
  for (int kk = 0; kk < 6; ++kk) {
    unsigned short* mp = mol16 + ((size_t)(kb + kk) * B_N + b) * 256 + 4 * lane;
    *(uint2*)mp = make_uint2(pk2(m[kk].x, m[kk].y), pk2(m[kk].z, m[kk].w));
  }

  // ---- coalesced atom_out write from wv32 ---------------------------------
#pragma unroll
  for (int i = tid; i < 192; i += 128) {
    const int kk = i >> 4, t0 = (i & 15) * 4;
    const float4 v = *(const float4*)&wv32[kk * 68 + t0];
    *(float4*)&out_atom[((size_t)kk * B_N + b) * T_N + t0] = v;
  }
}

// ---------------------------------------------------------------------------
// MFMA GEMM layer (unchanged; folded bn_coef in AFFINE prologue).
// ---------------------------------------------------------------------------
template <int S, bool AFFINE>
__global__ __launch_bounds__(256) void gemm_mfma(
    const unsigned* __restrict__ Abf, const unsigned* __restrict__ wpack,
    const float* __restrict__ bias,
    const float* __restrict__ ssum_p, const float* __restrict__ ssq_p,
    const float* __restrict__ g_p, const float* __restrict__ be_p,
    unsigned short* __restrict__ Hout,
    float* __restrict__ ssum, float* __restrict__ ssq)
{
  __shared__ unsigned tile[64 * S * 16];
  __shared__ float redS[4][8][16];
  __shared__ float redQ[4][8][16];
  __shared__ float alds[H_N], blds[H_N];

  const int k   = blockIdx.y;
  const int b0  = blockIdx.x << 6;
  const int tid = threadIdx.x;
  const int lane = tid & 63;
  const int wv  = tid >> 6;
  const int ln15 = lane & 15;
  const int hq   = lane >> 4;

  if (AFFINE) {
    if (tid < H_N) {
      const float inv_n = 1.f / (float)B_N;
      const float m = ssum_p[k * H_N + tid] * inv_n;
      float v = fmaf(ssq_p[k * H_N + tid], inv_n, -m * m);
      v = fmaxf(v, 0.f);
      const float a = g_p[k * H_N + tid] * rsqrtf(v + 1e-5f);
      alds[tid] = a;
      blds[tid] = fmaf(-m, a, be_p[k * H_N + tid]);
    }
    __syncthreads();
  }

  {
    const int row = tid >> 2, q = tid & 3;
    const uint4* Ar = (const uint4*)Abf + ((size_t)k * B_N + b0 + row) * (S * 4) + q * S;
#pragma unroll
    for (int gi = 0; gi < S; ++gi) {
      const int g = q * S + gi;
      uint4 u = Ar[gi];
      if (AFFINE) {
        const float4 al0 = *(const float4*)(alds + g * 8);
        const float4 al1 = *(const float4*)(alds + g * 8 + 4);
        const float4 bt0 = *(const float4*)(blds + g * 8);
        const float4 bt1 = *(const float4*)(blds + g * 8 + 4);
        u.x = pk2(fmaf(lo16(u.x), al0.x, bt0.x), fmaf(hi16(u.x), al0.y, bt0.y));
        u.y = pk2(fmaf(lo16(u.y), al0.z, bt0.z), fmaf(hi16(u.y), al0.w, bt0.w));
        u.z = pk2(fmaf(lo16(u.z), al1.x, bt1.x), fmaf(hi16(u.z), al1.y, bt1.y));
        u.w = pk2(fmaf(lo16(u.w), al1.z, bt1.z), fmaf(hi16(u.w), al1.w, bt1.w));
      }
      *(uint4*)&tile[row * (S * 16) + ((g ^ (row & 15)) << 2)] = u;
    }
  }
  __syncthreads();

  const short8* wp8 = (const short8*)wpack + (size_t)k * 8 * S * 64 + lane;
  f32x4 acc[8];
#pragma unroll
  for (int nt = 0; nt < 8; ++nt) acc[nt] = (f32x4){0.f, 0.f, 0.f, 0.f};

  short8 bs0[8], bs1[8];
#pragma unroll
  for (int nt = 0; nt < 8; ++nt) bs0[nt] = wp8[(nt * S) * 64];
#pragma unroll
  for (int s = 0; s < S; ++s) {
    if (s + 1 < S) {
#pragma unroll
      for (int nt = 0; nt < 8; ++nt) {
        if (s & 1) bs0[nt] = wp8[(nt * S + s + 1) * 64];
        else       bs1[nt] = wp8[(nt * S + s + 1) * 64];
      }
    }
    const int arow = (wv << 4) + ln15;
    const unsigned aoff = arow * (S * 16) + (((4 * s + hq) ^ ln15) << 2);
    const short8 af = *(const short8*)&tile[aoff];
#pragma unroll
    for (int nt = 0; nt < 8; ++nt) {
      const short8 bf = (s & 1) ? bs1[nt] : bs0[nt];
      acc[nt] = __builtin_amdgcn_mfma_f32_16x16x32_bf16(af, bf, acc[nt], 0, 0, 0);
    }
  }

#pragma unroll
  for (int nt = 0; nt < 8; ++nt) {
    const int col = nt * 16 + ln15;
    const float bv = bias[k * H_N + col];
    float cs = 0.f, cq = 0.f;
#pragma unroll
    for (int r = 0; r < 4; ++r) {
      const float o = fmaxf(acc[nt][r] + bv, 0.f);
      cs += o; cq = fmaf(o, o, cq);
      const int row = b0 + (wv << 4) + (hq << 2) + r;
      Hout[((size_t)k * B_N + row) * H_N + col] = (unsigned short)bf16_rne(o);
    }
    cs += __shfl_xor(cs, 16); cs += __shfl_xor(cs, 32);
    cq += __shfl_xor(cq, 16); cq += __shfl_xor(cq, 32);
    if (lane < 16) { redS[wv][nt][ln15] = cs; redQ[wv][nt][ln15] = cq; }
  }
  __syncthreads();
  if (tid < 128) {
    const int nt = tid >> 4, c = tid & 15;
    float s = 0.f, q = 0.f;
#pragma unroll
    for (int i = 0; i < 4; ++i) { s += redS[i][nt][c]; q += redQ[i][nt][c]; }
    atomicAdd(&ssum[k * H_N + nt * 16 + c], s);
    atomicAdd(&ssq[k * H_N + nt * 16 + c], q);
  }
}

// ---------------------------------------------------------------------------
// k_pred with folded bn3 (unchanged).
// ---------------------------------------------------------------------------
__global__ __launch_bounds__(256) void k_pred(
    const unsigned* __restrict__ h3,
    const float* __restrict__ s3, const float* __restrict__ q3,
    const float* __restrict__ g3, const float* __restrict__ be3,
    const float* __restrict__ Wout, const float* __restrict__ bout,
    float* __restrict__ out)
{
  const int lane = threadIdx.x & 63;
  const int wv   = threadIdx.x >> 6;
  const int pair = blockIdx.x * 4 + wv;
  const int b = pair / K_N, k = pair - b * K_N;
  const int i0 = k * H_N + (lane << 1);

  const float inv_n = 1.f / (float)B_N;
  const float2 sv = *(const float2*)(s3 + i0);
  const float2 qv = *(const float2*)(q3 + i0);
  const float2 gv = *(const float2*)(g3 + i0);
  const float2 bev = *(const float2*)(be3 + i0);
  const float mx = sv.x * inv_n, my = sv.y * inv_n;
  const float vx = fmaxf(fmaf(qv.x, inv_n, -mx * mx), 0.f);
  const float vy = fmaxf(fmaf(qv.y, inv_n, -my * my), 0.f);
  const float ax = gv.x * rsqrtf(vx + 1e-5f);
  const float ay = gv.y * rsqrtf(vy + 1e-5f);
  const float bx = fmaf(-mx, ax, bev.x);
  const float by = fmaf(-my, ay, bev.y);

  const unsigned xp = h3[((size_t)k * B_N + b) * 64 + lane];
  const float2 wo = *(const float2*)(Wout + i0);
  float s = fmaf(lo16(xp), ax, bx) * wo.x + fmaf(hi16(xp), ay, by) * wo.y;
#pragma unroll
  for (int off = 32; off; off >>= 1) s += __shfl_down(s, off);
  if (lane == 0) out[pair] = s + bout[k];
}

extern "C" void kernel_launch(void* const* d_in, const int* in_sizes, int n_in,
                              void* d_out, int out_size, void* d_ws, size_t ws_size,
                              hipStream_t stream)
{
  (void)in_sizes; (void)n_in; (void)out_size; (void)ws_size;
  const int*   dx     = (const int*)d_in[0];
  const float* feats  = (const float*)d_in[1];
  const float* w_atom = (const float*)d_in[2];
  const float* b_atom = (const float*)d_in[3];
  const float* W1 = (const float*)d_in[4];
  const float* b1 = (const float*)d_in[5];
  const float* g1 = (const float*)d_in[6];
  const float* be1 = (const float*)d_in[7];
  const float* W2 = (const float*)d_in[8];
  const float* b2 = (const float*)d_in[9];
  const float* g2 = (const float*)d_in[10];
  const float* be2 = (const float*)d_in[11];
  const float* W3 = (const float*)d_in[12];
  const float* b3 = (const float*)d_in[13];
  const float* g3 = (const float*)d_in[14];
  const float* be3 = (const float*)d_in[15];
  const float* Wout = (const float*)d_in[16];
  const float* bout = (const float*)d_in[17];

  float* out      = (float*)d_out;
  float* pred_out = out;                       // (B, K)
  float* atom_out = out + (size_t)B_N * K_N;   // (K, B, T)

  // ---- workspace layout (bytes) ----
  char* wsb = (char*)d_ws;
  unsigned short* mol16 = (unsigned short*)wsb;                // bf16 K*B*D
  unsigned short* h1   = (unsigned short*)(wsb + 25165824);
  unsigned short* h2   = (unsigned short*)(wsb + 37748736);
  unsigned short* h3   = (unsigned short*)(wsb + 50331648);
  float* st = (float*)(wsb + 62914560);                        // 9216 floats
  float* s1 = st,        *q1 = st + 1536;
  float* s2 = st + 3072, *q2 = st + 4608;
  float* s3 = st + 6144, *q3 = st + 7680;
  unsigned* wa_frag = (unsigned*)(st + 9216);
  unsigned* w1p = wa_frag + 2048;
  unsigned* w2p = w1p + 196608;
  unsigned* w3p = w2p + 98304;

  prep_all<<<422, 256, 0, stream>>>(w_atom, W1, W2, W3, wa_frag, w1p, w2p, w3p, st);

  k1_mol<<<B_N, 128, 0, stream>>>(dx, feats, wa_frag, b_atom, atom_out, mol16);

  gemm_mfma<8, false><<<dim3(64, 12), 256, 0, stream>>>(
      (const unsigned*)mol16, w1p, b1, nullptr, nullptr, nullptr, nullptr, h1, s1, q1);
  gemm_mfma<4, true><<<dim3(64, 12), 256, 0, stream>>>(
      (const unsigned*)h1, w2p, b2, s1, q1, g1, be1, h2, s2, q2);
  gemm_mfma<4, true><<<dim3(64, 12), 256, 0, stream>>>(
      (const unsigned*)h2, w3p, b3, s2, q2, g2, be2, h3, s3, q3);
  k_pred<<<B_N * K_N / 4, 256, 0, stream>>>(
      (const unsigned*)h3, s3, q3, g3, be3, Wout, bout, pred_out);
}

// Round 18
// 124.009 us; speedup vs baseline: 1.6727x; 1.0762x over previous
//
#include <hip/hip_runtime.h>
#include <hip/hip_bf16.h>

#define B_N 4096
#define T_N 64
#define D_N 256
#define H_N 128
#define K_N 12

typedef __attribute__((ext_vector_type(8))) short short8;
typedef __attribute__((ext_vector_type(4))) float f32x4;

static __device__ __forceinline__ unsigned bf16_rne(float x) {
  unsigned u = __float_as_uint(x);
  return (u + 0x7fffu + ((u >> 16) & 1u)) >> 16;
}
static __device__ __forceinline__ unsigned pk2(float a, float b) {
  return bf16_rne(a) | (bf16_rne(b) << 16);
}
static __device__ __forceinline__ float lo16(unsigned u) { return __uint_as_float(u << 16); }
static __device__ __forceinline__ float hi16(unsigned u) { return __uint_as_float(u & 0xffff0000u); }

// ---------------------------------------------------------------------------
// prep_all: ONE kernel replacing prep_wa + 3x prep_w + stats memset.
// Block ranges: [0,2) wa_frag | [2,194) w1p(S=8) | [194,290) w2p(S=4) |
// [290,386) w3p(S=4) | [386,422) zero stats (9216 floats).
// ---------------------------------------------------------------------------
__device__ __forceinline__ void pack_w(const float* W, unsigned* out, int S, int id) {
  const int lane = id & 63;
  const int s  = (id >> 6) % S;
  const int nt = ((id >> 6) / S) & 7;
  const int kk = id / (64 * S * 8);
  const int n  = nt * 16 + (lane & 15);
  const int d0 = 32 * s + 8 * (lane >> 4);
  const int D  = 32 * S;
  unsigned o[4];
#pragma unroll
  for (int j = 0; j < 4; ++j) {
    const float a = W[(size_t)kk * D * H_N + (d0 + 2 * j) * H_N + n];
    const float b = W[(size_t)kk * D * H_N + (d0 + 2 * j + 1) * H_N + n];
    o[j] = pk2(a, b);
  }
  *(uint4*)(out + (size_t)id * 4) = make_uint4(o[0], o[1], o[2], o[3]);
}

__global__ void prep_all(const float* __restrict__ w_atom,
                         const float* __restrict__ W1, const float* __restrict__ W2,
                         const float* __restrict__ W3,
                         unsigned* __restrict__ wa_frag, unsigned* __restrict__ w1p,
                         unsigned* __restrict__ w2p, unsigned* __restrict__ w3p,
                         float* __restrict__ st)
{
  const int bid = blockIdx.x, tid = threadIdx.x;
  if (bid < 2) {
    const int id = bid * 256 + tid;          // [0,512)
    const int s = id >> 6, l = id & 63;
    const int k = l & 15, h = l >> 4, d0 = s * 32 + h * 8;
    unsigned o[4];
#pragma unroll
    for (int j = 0; j < 4; ++j) {
      const float a = (k < K_N) ? w_atom[k * D_N + d0 + 2 * j]     : 0.f;
      const float b = (k < K_N) ? w_atom[k * D_N + d0 + 2 * j + 1] : 0.f;
      o[j] = pk2(a, b);
    }
    *(uint4*)(wa_frag + (size_t)id * 4) = make_uint4(o[0], o[1], o[2], o[3]);
  } else if (bid < 194) {
    pack_w(W1, w1p, 8, (bid - 2) * 256 + tid);
  } else if (bid < 290) {
    pack_w(W2, w2p, 4, (bid - 194) * 256 + tid);
  } else if (bid < 386) {
    pack_w(W3, w3p, 4, (bid - 290) * 256 + tid);
  } else {
    const int id = (bid - 386) * 256 + tid;
    if (id < 9216) st[id] = 0.f;
  }
}

// ---------------------------------------------------------------------------
// K1 (best known / R13): one block per b, 4 waves, no stage barrier.
// ---------------------------------------------------------------------------
__global__ __launch_bounds__(256, 4) void k1_mol(
    const int* __restrict__ dx, const float* __restrict__ feats,
    const unsigned* __restrict__ wa_frag, const float* __restrict__ b_atom,
    float* __restrict__ out_atom, unsigned* __restrict__ molb)
{
  __shared__ unsigned tile[64 * 128];   // 32 KB bf16 tile, 16B-granule swizzle
  __shared__ float wv32[K_N * 64];

  const int tid  = threadIdx.x;
  const int lane = tid & 63;
  const int w    = tid >> 6;
  const int b    = blockIdx.x;
  const int k    = lane & 15;
  const int h    = lane >> 4;

  short8 bfr[8];
  {
    const short8* wf8 = (const short8*)wa_frag;
#pragma unroll
    for (int s = 0; s < 8; ++s) bfr[s] = wf8[s * 64 + lane];
  }
  const float ba = (k < K_N) ? b_atom[k] : 0.f;
  const int4 dvv = *(const int4*)(dx + b * T_N + 16 * w + 4 * h);

  const float* fg = feats + ((size_t)b * 65 + 1) * 256;
#pragma unroll
  for (int c = 0; c < 4; ++c) {
    float4 v[4];
#pragma unroll
    for (int i = 0; i < 4; ++i)
      v[i] = *(const float4*)(fg + (size_t)(16 * w + 4 * c + i) * 256 + 4 * lane);
#pragma unroll
    for (int i = 0; i < 4; ++i) {
      const int tl = 4 * c + i;
      const int t  = 16 * w + tl;
      const unsigned off = t * 128 + (((lane >> 1) ^ tl) << 2) + (lane & 1) * 2;
      *(uint2*)&tile[off] = make_uint2(pk2(v[i].x, v[i].y), pk2(v[i].z, v[i].w));
    }
  }
  // No barrier: phase 1 reads only this wave's rows (lgkmcnt ordering).

  f32x4 cacc = {0.f, 0.f, 0.f, 0.f};
#pragma unroll
  for (int s = 0; s < 8; ++s) {
    const unsigned off = (16 * w + k) * 128 + (((4 * s + h) ^ k) << 2);
    const short8 afrag = *(const short8*)&tile[off];
    cacc = __builtin_amdgcn_mfma_f32_16x16x32_bf16(afrag, bfr[s], cacc, 0, 0, 0);
  }

#pragma unroll
  for (int r = 0; r < 4; ++r) {
    const float valid = (((const int*)&dvv)[r] != 0) ? 1.f : 0.f;
    const float wv = valid / (1.f + __expf(-(cacc[r] + ba)));
    if (k < K_N) wv32[k * 64 + 16 * w + 4 * h + r] = wv;
  }
  __syncthreads();   // wv32 + full tile visible before phase 2

  const int kb = w * 3;
  float4 m0 = make_float4(0.f, 0.f, 0.f, 0.f), m1 = m0, m2 = m0;
#pragma unroll
  for (int tc = 0; tc < 16; ++tc) {
    const float4 wv0 = *(const float4*)&wv32[(kb + 0) * 64 + (tc << 2)];
    const float4 wv1 = *(const float4*)&wv32[(kb + 1) * 64 + (tc << 2)];
    const float4 wv2 = *(const float4*)&wv32[(kb + 2) * 64 + (tc << 2)];
    const float w0a[4] = {wv0.x, wv0.y, wv0.z, wv0.w};
    const float w1a[4] = {wv1.x, wv1.y, wv1.z, wv1.w};
    const float w2a[4] = {wv2.x, wv2.y, wv2.z, wv2.w};
#pragma unroll
    for (int j = 0; j < 4; ++j) {
      const int t = (tc << 2) + j;
      const unsigned off = t * 128 + (((lane >> 1) ^ (t & 15)) << 2) + (lane & 1) * 2;
      const uint2 pw = *(const uint2*)&tile[off];
      const float f0 = lo16(pw.x), f1 = hi16(pw.x);
      const float f2 = lo16(pw.y), f3 = hi16(pw.y);
      m0.x = fmaf(w0a[j], f0, m0.x); m0.y = fmaf(w0a[j], f1, m0.y);
      m0.z = fmaf(w0a[j], f2, m0.z); m0.w = fmaf(w0a[j], f3, m0.w);
      m1.x = fmaf(w1a[j], f0, m1.x); m1.y = fmaf(w1a[j], f1, m1.y);
      m1.z = fmaf(w1a[j], f2, m1.z); m1.w = fmaf(w1a[j], f3, m1.w);
      m2.x = fmaf(w2a[j], f0, m2.x); m2.y = fmaf(w2a[j], f1, m2.y);
      m2.z = fmaf(w2a[j], f2, m2.z); m2.w = fmaf(w2a[j], f3, m2.w);
    }
  }
  unsigned* mpb = molb + ((size_t)kb * B_N + b) * 128 + (lane << 1);
  *(uint2*)(mpb)                         = make_uint2(pk2(m0.x, m0.y), pk2(m0.z, m0.w));
  *(uint2*)(mpb + (size_t)B_N * 128)     = make_uint2(pk2(m1.x, m1.y), pk2(m1.z, m1.w));
  *(uint2*)(mpb + (size_t)2 * B_N * 128) = make_uint2(pk2(m2.x, m2.y), pk2(m2.z, m2.w));

  if (tid < 192) {
    const float4 v = *(const float4*)&wv32[tid * 4];
    const int kk = tid >> 4, t0 = (tid & 15) * 4;
    *(float4*)&out_atom[((size_t)kk * B_N + b) * T_N + t0] = v;
  }
}

// ---------------------------------------------------------------------------
// MFMA GEMM layer (folded bn_coef in AFFINE prologue).
// ---------------------------------------------------------------------------
template <int S, bool AFFINE>
__global__ __launch_bounds__(256) void gemm_mfma(
    const unsigned* __restrict__ Abf, const unsigned* __restrict__ wpack,
    const float* __restrict__ bias,
    const float* __restrict__ ssum_p, const float* __restrict__ ssq_p,
    const float* __restrict__ g_p, const float* __restrict__ be_p,
    unsigned short* __restrict__ Hout,
    float* __restrict__ ssum, float* __restrict__ ssq)
{
  __shared__ unsigned tile[64 * S * 16];
  __shared__ float redS[4][8][16];
  __shared__ float redQ[4][8][16];
  __shared__ float alds[H_N], blds[H_N];

  const int k   = blockIdx.y;
  const int b0  = blockIdx.x << 6;
  const int tid = threadIdx.x;
  const int lane = tid & 63;
  const int wv  = tid >> 6;
  const int ln15 = lane & 15;
  const int hq   = lane >> 4;

  if (AFFINE) {   // folded bn_coef: per-block re-derivation for this k
    if (tid < H_N) {
      const float inv_n = 1.f / (float)B_N;
      const float m = ssum_p[k * H_N + tid] * inv_n;
      float v = fmaf(ssq_p[k * H_N + tid], inv_n, -m * m);
      v = fmaxf(v, 0.f);
      const float a = g_p[k * H_N + tid] * rsqrtf(v + 1e-5f);
      alds[tid] = a;
      blds[tid] = fmaf(-m, a, be_p[k * H_N + tid]);
    }
    __syncthreads();
  }

  {
    const int row = tid >> 2, q = tid & 3;
    const uint4* Ar = (const uint4*)Abf + ((size_t)k * B_N + b0 + row) * (S * 4) + q * S;
#pragma unroll
    for (int gi = 0; gi < S; ++gi) {
      const int g = q * S + gi;
      uint4 u = Ar[gi];
      if (AFFINE) {
        const float4 al0 = *(const float4*)(alds + g * 8);
        const float4 al1 = *(const float4*)(alds + g * 8 + 4);
        const float4 bt0 = *(const float4*)(blds + g * 8);
        const float4 bt1 = *(const float4*)(blds + g * 8 + 4);
        u.x = pk2(fmaf(lo16(u.x), al0.x, bt0.x), fmaf(hi16(u.x), al0.y, bt0.y));
        u.y = pk2(fmaf(lo16(u.y), al0.z, bt0.z), fmaf(hi16(u.y), al0.w, bt0.w));
        u.z = pk2(fmaf(lo16(u.z), al1.x, bt1.x), fmaf(hi16(u.z), al1.y, bt1.y));
        u.w = pk2(fmaf(lo16(u.w), al1.z, bt1.z), fmaf(hi16(u.w), al1.w, bt1.w));
      }
      *(uint4*)&tile[row * (S * 16) + ((g ^ (row & 15)) << 2)] = u;
    }
  }
  __syncthreads();

  const short8* wp8 = (const short8*)wpack + (size_t)k * 8 * S * 64 + lane;
  f32x4 acc[8];
#pragma unroll
  for (int nt = 0; nt < 8; ++nt) acc[nt] = (f32x4){0.f, 0.f, 0.f, 0.f};

  short8 bs0[8], bs1[8];
#pragma unroll
  for (int nt = 0; nt < 8; ++nt) bs0[nt] = wp8[(nt * S) * 64];
#pragma unroll
  for (int s = 0; s < S; ++s) {
    if (s + 1 < S) {
#pragma unroll
      for (int nt = 0; nt < 8; ++nt) {
        if (s & 1) bs0[nt] = wp8[(nt * S + s + 1) * 64];
        else       bs1[nt] = wp8[(nt * S + s + 1) * 64];
      }
    }
    const int arow = (wv << 4) + ln15;
    const unsigned aoff = arow * (S * 16) + (((4 * s + hq) ^ ln15) << 2);
    const short8 af = *(const short8*)&tile[aoff];
#pragma unroll
    for (int nt = 0; nt < 8; ++nt) {
      const short8 bf = (s & 1) ? bs1[nt] : bs0[nt];
      acc[nt] = __builtin_amdgcn_mfma_f32_16x16x32_bf16(af, bf, acc[nt], 0, 0, 0);
    }
  }

#pragma unroll
  for (int nt = 0; nt < 8; ++nt) {
    const int col = nt * 16 + ln15;
    const float bv = bias[k * H_N + col];
    float cs = 0.f, cq = 0.f;
#pragma unroll
    for (int r = 0; r < 4; ++r) {
      const float o = fmaxf(acc[nt][r] + bv, 0.f);
      cs += o; cq = fmaf(o, o, cq);
      const int row = b0 + (wv << 4) + (hq << 2) + r;
      Hout[((size_t)k * B_N + row) * H_N + col] = (unsigned short)bf16_rne(o);
    }
    cs += __shfl_xor(cs, 16); cs += __shfl_xor(cs, 32);
    cq += __shfl_xor(cq, 16); cq += __shfl_xor(cq, 32);
    if (lane < 16) { redS[wv][nt][ln15] = cs; redQ[wv][nt][ln15] = cq; }
  }
  __syncthreads();
  if (tid < 128) {
    const int nt = tid >> 4, c = tid & 15;
    float s = 0.f, q = 0.f;
#pragma unroll
    for (int i = 0; i < 4; ++i) { s += redS[i][nt][c]; q += redQ[i][nt][c]; }
    atomicAdd(&ssum[k * H_N + nt * 16 + c], s);
    atomicAdd(&ssq[k * H_N + nt * 16 + c], q);
  }
}

// ---------------------------------------------------------------------------
// k_pred with folded bn3: derives alpha/beta for its (k, 2 h's) inline from
// layer-3 stats (complete after gemm3 retires).
// ---------------------------------------------------------------------------
__global__ __launch_bounds__(256) void k_pred(
    const unsigned* __restrict__ h3,
    const float* __restrict__ s3, const float* __restrict__ q3,
    const float* __restrict__ g3, const float* __restrict__ be3,
    const float* __restrict__ Wout, const float* __restrict__ bout,
    float* __restrict__ out)
{
  const int lane = threadIdx.x & 63;
  const int wv   = threadIdx.x >> 6;
  const int pair = blockIdx.x * 4 + wv;
  const int b = pair / K_N, k = pair - b * K_N;
  const int i0 = k * H_N + (lane << 1);

  const float inv_n = 1.f / (float)B_N;
  const float2 sv = *(const float2*)(s3 + i0);
  const float2 qv = *(const float2*)(q3 + i0);
  const float2 gv = *(const float2*)(g3 + i0);
  const float2 bev = *(const float2*)(be3 + i0);
  const float mx = sv.x * inv_n, my = sv.y * inv_n;
  const float vx = fmaxf(fmaf(qv.x, inv_n, -mx * mx), 0.f);
  const float vy = fmaxf(fmaf(qv.y, inv_n, -my * my), 0.f);
  const float ax = gv.x * rsqrtf(vx + 1e-5f);
  const float ay = gv.y * rsqrtf(vy + 1e-5f);
  const float bx = fmaf(-mx, ax, bev.x);
  const float by = fmaf(-my, ay, bev.y);

  const unsigned xp = h3[((size_t)k * B_N + b) * 64 + lane];
  const float2 wo = *(const float2*)(Wout + i0);
  float s = fmaf(lo16(xp), ax, bx) * wo.x + fmaf(hi16(xp), ay, by) * wo.y;
#pragma unroll
  for (int off = 32; off; off >>= 1) s += __shfl_down(s, off);
  if (lane == 0) out[pair] = s + bout[k];
}

extern "C" void kernel_launch(void* const* d_in, const int* in_sizes, int n_in,
                              void* d_out, int out_size, void* d_ws, size_t ws_size,
                              hipStream_t stream)
{
  (void)in_sizes; (void)n_in; (void)out_size; (void)ws_size;
  const int*   dx     = (const int*)d_in[0];
  const float* feats  = (const float*)d_in[1];
  const float* w_atom = (const float*)d_in[2];
  const float* b_atom = (const float*)d_in[3];
  const float* W1 = (const float*)d_in[4];
  const float* b1 = (const float*)d_in[5];
  const float* g1 = (const float*)d_in[6];
  const float* be1 = (const float*)d_in[7];
  const float* W2 = (const float*)d_in[8];
  const float* b2 = (const float*)d_in[9];
  const float* g2 = (const float*)d_in[10];
  const float* be2 = (const float*)d_in[11];
  const float* W3 = (const float*)d_in[12];
  const float* b3 = (const float*)d_in[13];
  const float* g3 = (const float*)d_in[14];
  const float* be3 = (const float*)d_in[15];
  const float* Wout = (const float*)d_in[16];
  const float* bout = (const float*)d_in[17];

  float* out      = (float*)d_out;
  float* pred_out = out;                       // (B, K)
  float* atom_out = out + (size_t)B_N * K_N;   // (K, B, T)

  // ---- workspace layout (bytes) ----
  char* wsb = (char*)d_ws;
  unsigned*       molb = (unsigned*)wsb;                       // bf16 K*B*D
  unsigned short* h1   = (unsigned short*)(wsb + 25165824);
  unsigned short* h2   = (unsigned short*)(wsb + 37748736);
  unsigned short* h3   = (unsigned short*)(wsb + 50331648);
  float* st = (float*)(wsb + 62914560);                        // 9216 floats
  float* s1 = st,        *q1 = st + 1536;
  float* s2 = st + 3072, *q2 = st + 4608;
  float* s3 = st + 6144, *q3 = st + 7680;
  unsigned* wa_frag = (unsigned*)(st + 9216);
  unsigned* w1p = wa_frag + 2048;
  unsigned* w2p = w1p + 196608;
  unsigned* w3p = w2p + 98304;

  prep_all<<<422, 256, 0, stream>>>(w_atom, W1, W2, W3, wa_frag, w1p, w2p, w3p, st);

  k1_mol<<<B_N, 256, 0, stream>>>(dx, feats, wa_frag, b_atom, atom_out, molb);

  gemm_mfma<8, false><<<dim3(64, 12), 256, 0, stream>>>(
      molb, w1p, b1, nullptr, nullptr, nullptr, nullptr, h1, s1, q1);
  gemm_mfma<4, true><<<dim3(64, 12), 256, 0, stream>>>(
      (const unsigned*)h1, w2p, b2, s1, q1, g1, be1, h2, s2, q2);
  gemm_mfma<4, true><<<dim3(64, 12), 256, 0, stream>>>(
      (const unsigned*)h2, w3p, b3, s2, q2, g2, be2, h3, s3, q3);
  k_pred<<<B_N * K_N / 4, 256, 0, stream>>>(
      (const unsigned*)h3, s3, q3, g3, be3, Wout, bout, pred_out);
}